// Round 2
// baseline (510.641 us; speedup 1.0000x reference)
//
#include <hip/hip_runtime.h>
#include <hip/hip_bf16.h>

#define BB 16
#define SS 2048
#define DD 64
#define NT_TILES (SS / 128)     // 16 k-tiles per batch
#define TILE_BYTES 16384        // one prepacked tile image (K or V^T), bf16 swizzled

typedef __attribute__((ext_vector_type(8)))  unsigned short ushort8;
typedef __attribute__((ext_vector_type(8)))  __bf16 bf16x8;
typedef __attribute__((ext_vector_type(16))) float f32x16;
typedef __attribute__((ext_vector_type(4)))  unsigned int uint4v;

static __device__ __forceinline__ unsigned short f2bf(float x) {
    return __builtin_bit_cast(unsigned short, __float2bfloat16(x));
}
static __device__ __forceinline__ unsigned pk2(float a, float b) {
    return (unsigned)f2bf(a) | ((unsigned)f2bf(b) << 16);
}
union F4 { float4 v; float a[4]; };

// ---------------------------------------------------------------------------
// Pre-pack (unchanged from verified r1): fp32 K,V -> bf16 swizzled 16KB tile
// images in workspace. One block per (k-tile, batch).
// ---------------------------------------------------------------------------
__global__ __launch_bounds__(256)
void prepack_kernel(const float* __restrict__ K, const float* __restrict__ V,
                    char* __restrict__ wsK, char* __restrict__ wsV) {
    __shared__ __align__(16) char smem[32768];
    char* Ks = smem;
    char* Vs = smem + 16384;
    const int t  = threadIdx.x;
    const int kt = blockIdx.x;
    const int b  = blockIdx.y;
    const float* Kg = K + (size_t)b * SS * DD;
    const float* Vg = V + (size_t)b * SS * DD;

    // K tile 128x64: flat coalesced float4 pairs -> swizzled b128 granules
    #pragma unroll
    for (int j = 0; j < 4; j++) {
        const int idx = 2 * t + 512 * j;
        const int row = idx >> 4;
        const int g   = (idx & 15) >> 1;
        const float* src = Kg + (size_t)(kt * 128) * DD + (size_t)idx * 4;
        F4 fa, fb; fa.v = *(const float4*)src; fb.v = *(const float4*)(src + 4);
        ushort8 u;
        #pragma unroll
        for (int e = 0; e < 4; e++) { u[e] = f2bf(fa.a[e]); u[e + 4] = f2bf(fb.a[e]); }
        *(ushort8*)(Ks + row * 128 + ((g ^ (row & 7)) * 16)) = u;
    }
    // V tile transposed: Vs[d][k], pitch 256, 16-granule XOR swizzle
    {
        const int d0v = (t & 15) * 4;
        const int kkb = (t >> 4) * 4;
        #pragma unroll
        for (int it2 = 0; it2 < 2; it2++) {
            const int kk = kkb + 64 * it2;
            const float* src = Vg + (size_t)(kt * 128 + kk) * DD + d0v;
            F4 r0, r1, r2, r3;
            r0.v = *(const float4*)(src);
            r1.v = *(const float4*)(src + DD);
            r2.v = *(const float4*)(src + 2 * DD);
            r3.v = *(const float4*)(src + 3 * DD);
            #pragma unroll
            for (int e = 0; e < 4; e++) {
                const int d = d0v + e;
                const uint2 wv = make_uint2(pk2(r0.a[e], r1.a[e]), pk2(r2.a[e], r3.a[e]));
                *(uint2*)(Vs + d * 256 + (((kk >> 3) ^ (d & 15)) * 16) + (kk & 7) * 2) = wv;
            }
        }
    }
    __syncthreads();
    // linear dump of the finished images (fully coalesced both sides)
    char* dK = wsK + (size_t)(b * NT_TILES + kt) * TILE_BYTES;
    char* dV = wsV + (size_t)(b * NT_TILES + kt) * TILE_BYTES;
    #pragma unroll
    for (int j = 0; j < 4; j++) {
        *(float4*)(dK + t * 16 + j * 4096) = *(const float4*)(Ks + t * 16 + j * 4096);
        *(float4*)(dV + t * 16 + j * 4096) = *(const float4*)(Vs + t * 16 + j * 4096);
    }
}

// ---------------------------------------------------------------------------
// Main kernel: BARRIER-FREE k-loop. MFMA fragments are read directly from the
// prepacked swizzled global images (L2-resident: 512 KB/batch) with the exact
// same address formulas the LDS reads used; mask words are read directly as
// per-lane nontemporal uint4 (each word consumed by exactly one lane, once).
// No LDS, no __syncthreads, no vmcnt(0) drain in the loop -> the compiler
// software-pipelines loads across iterations freely (Common-mistake #7 fix:
// don't LDS-stage data that L2-fits). LDS only for Q prestage + epilogue.
// ---------------------------------------------------------------------------
__global__ __launch_bounds__(256, 4)
void sdpa_mfma_kernel(const float* __restrict__ Q, const char* __restrict__ wsK,
                      const char* __restrict__ wsV, const unsigned int* __restrict__ M,
                      float* __restrict__ O) {
    __shared__ __align__(16) char smem[25088];
    char* Qs = smem;                         // pre-loop only (4 KB, overlaps red)
    float* red  = (float*)smem;              // epilogue partials (24 KB)
    float* denx = (float*)(smem + 24576);    // epilogue den exchange (512 B)

    const int t    = threadIdx.x;
    const int lane = t & 63;
    const int l31  = lane & 31;
    const int half = lane >> 5;
    const int kh   = t >> 6;          // wave = k-chunk 32*kh of the 128-tile
    const int b    = blockIdx.y;
    const int q0   = blockIdx.x * 32;

    // ---- stage Q (pre-scaled by 1/temperature), swizzled bf16 ----
    {
        const int sr = t >> 3, sc = t & 7;
        const float* src = Q + ((size_t)b * SS + q0 + sr) * DD + sc * 8;
        F4 f0, f1; f0.v = *(const float4*)src; f1.v = *(const float4*)(src + 4);
        ushort8 u;
        #pragma unroll
        for (int e = 0; e < 4; e++) {
            u[e]     = f2bf(f0.a[e] * 0.125f);
            u[e + 4] = f2bf(f1.a[e] * 0.125f);
        }
        *(ushort8*)(Qs + sr * 128 + ((sc ^ (sr & 7)) * 16)) = u;
    }
    __syncthreads();

    // ---- preload Q fragments (B operand); all 4 waves share the q-tile ----
    const int qrow = l31;
    bf16x8 bq[4];
    #pragma unroll
    for (int dc = 0; dc < 4; dc++)
        bq[dc] = __builtin_bit_cast(bf16x8, *(const ushort8*)(
            Qs + qrow * 128 + (((2 * dc + half) ^ (qrow & 7)) * 16)));
    // (no barrier needed: smem untouched until the epilogue barrier)

    f32x16 On0, On1;
    #pragma unroll
    for (int i = 0; i < 16; i++) { On0[i] = 0.f; On1[i] = 0.f; }
    float den_acc = 0.f;

    const int krow = 32 * kh + l31;
    const char* tKbase = wsK + (size_t)b * NT_TILES * TILE_BYTES;
    const char* tVbase = wsV + (size_t)b * NT_TILES * TILE_BYTES;
    // mask row pointer for this lane (word units); columns 32kh+8g+4half+e
    const unsigned int* Mrow = M + (size_t)b * SS * SS + (size_t)(q0 + qrow) * SS
                                 + 32 * kh + 4 * half;

    for (int kt = 0; kt < NT_TILES; ++kt) {
        const char* tK = tKbase + (size_t)kt * TILE_BYTES;
        const char* tV = tVbase + (size_t)kt * TILE_BYTES;

        // ---- issue all loads for this iteration up front (L2-resident K/V) ----
        bf16x8 ak[4];
        #pragma unroll
        for (int dc = 0; dc < 4; dc++)
            ak[dc] = __builtin_bit_cast(bf16x8, *(const ushort8*)(
                tK + krow * 128 + (((2 * dc + half) ^ (krow & 7)) * 16)));
        uint4v mw[4];
        #pragma unroll
        for (int g = 0; g < 4; g++)
            mw[g] = __builtin_nontemporal_load((const uint4v*)(Mrow + kt * 128 + 8 * g));
        bf16x8 av[2][2];
        #pragma unroll
        for (int s2 = 0; s2 < 2; s2++)
            #pragma unroll
            for (int dc = 0; dc < 2; dc++) {
                const int vrow = 32 * dc + l31;
                av[s2][dc] = __builtin_bit_cast(bf16x8, *(const ushort8*)(
                    tV + vrow * 256 + (((4 * kh + 2 * s2 + half) ^ (vrow & 15)) * 16)));
            }

        // ---- QK^T: S^T tile [32k x 32q] for this wave's k-chunk ----
        f32x16 S;
        #pragma unroll
        for (int i = 0; i < 16; i++) S[i] = 0.f;
        #pragma unroll
        for (int dc = 0; dc < 4; dc++)
            S = __builtin_amdgcn_mfma_f32_32x32x16_bf16(ak[dc], bq[dc], S, 0, 0, 0);

        // ---- mask + exp + denominator (C row = e + 8g + 4half) ----
        float p[16];
        #pragma unroll
        for (int g = 0; g < 4; g++) {
            #pragma unroll
            for (int e = 0; e < 4; e++) {
                const float ev = __expf(S[4 * g + e]);
                const float pv = mw[g][e] ? 1.0f : ev;
                p[4 * g + e] = pv;
                den_acc += pv;
            }
        }

        // ---- P·V: B-operand frags via shfl_xor(32) (proven r5), 2 ksubs ----
        #pragma unroll
        for (int s2 = 0; s2 < 2; s2++) {
            const unsigned o0 = pk2(p[8 * s2 + 0], p[8 * s2 + 1]);
            const unsigned o1 = pk2(p[8 * s2 + 2], p[8 * s2 + 3]);
            const unsigned o2 = pk2(p[8 * s2 + 4], p[8 * s2 + 5]);
            const unsigned o3 = pk2(p[8 * s2 + 6], p[8 * s2 + 7]);
            const unsigned s0 = half ? o0 : o2;
            const unsigned s1 = half ? o1 : o3;
            const unsigned r0 = (unsigned)__shfl_xor((int)s0, 32, 64);
            const unsigned r1 = (unsigned)__shfl_xor((int)s1, 32, 64);
            uint4 bu;
            bu.x = half ? r0 : o0;
            bu.y = half ? r1 : o1;
            bu.z = half ? o2 : r0;
            bu.w = half ? o3 : r1;
            const bf16x8 bp = __builtin_bit_cast(bf16x8, bu);
            #pragma unroll
            for (int dc = 0; dc < 2; dc++) {
                if (dc == 0) On0 = __builtin_amdgcn_mfma_f32_32x32x16_bf16(av[s2][0], bp, On0, 0, 0, 0);
                else         On1 = __builtin_amdgcn_mfma_f32_32x32x16_bf16(av[s2][1], bp, On1, 0, 0, 0);
            }
        }
    }

    // ---- epilogue: lane halves, then 4-way k-split reduction via LDS ----
    const float den_tot = den_acc + __shfl_xor(den_acc, 32, 64);

    __syncthreads();
    if (kh != 0) {
        #pragma unroll
        for (int dc = 0; dc < 2; dc++)
            #pragma unroll
            for (int g = 0; g < 4; g++) {
                const f32x16& Oc = dc ? On1 : On0;
                float4 st;
                st.x = Oc[4 * g + 0]; st.y = Oc[4 * g + 1];
                st.z = Oc[4 * g + 2]; st.w = Oc[4 * g + 3];
                *(float4*)((char*)red + (kh - 1) * 8192 + (dc * 4 + g) * 1024 + lane * 16) = st;
            }
        if (lane < 32) denx[kh * 32 + l31] = den_tot;
    }
    __syncthreads();
    if (kh == 0) {
        const float inv = 1.0f / (den_tot + denx[32 + l31] + denx[64 + l31] + denx[96 + l31]);
        float* Og = O + ((size_t)b * SS + q0 + qrow) * DD;
        #pragma unroll
        for (int dc = 0; dc < 2; dc++)
            #pragma unroll
            for (int g = 0; g < 4; g++) {
                const f32x16& Oc = dc ? On1 : On0;
                float4 st;
                st.x = Oc[4 * g + 0]; st.y = Oc[4 * g + 1];
                st.z = Oc[4 * g + 2]; st.w = Oc[4 * g + 3];
                #pragma unroll
                for (int w2 = 0; w2 < 3; w2++) {
                    const float4 pr = *(const float4*)((char*)red + w2 * 8192 +
                                                       (dc * 4 + g) * 1024 + lane * 16);
                    st.x += pr.x; st.y += pr.y; st.z += pr.z; st.w += pr.w;
                }
                st.x *= inv; st.y *= inv; st.z *= inv; st.w *= inv;
                // d = e + 8g + 4half + 32dc  (C-row formula)
                *(float4*)(Og + 32 * dc + 8 * g + 4 * half) = st;
            }
    }
}

extern "C" void kernel_launch(void* const* d_in, const int* in_sizes, int n_in,
                              void* d_out, int out_size, void* d_ws, size_t ws_size,
                              hipStream_t stream) {
    const float* q = (const float*)d_in[0];
    const float* k = (const float*)d_in[1];
    const float* v = (const float*)d_in[2];
    const unsigned int* m = (const unsigned int*)d_in[3];
    float* out = (float*)d_out;

    // workspace: 4 MB K images + 4 MB V images (bf16, swizzled tile layout)
    char* wsK = (char*)d_ws;
    char* wsV = (char*)d_ws + (size_t)BB * NT_TILES * TILE_BYTES;

    dim3 pgrid(NT_TILES, BB);           // 16 x 16 = 256 blocks, 1 per CU
    prepack_kernel<<<pgrid, 256, 0, stream>>>(k, v, wsK, wsV);

    dim3 grid(SS / 32, BB);             // 64 x 16 = 1024 blocks -> 4 per CU
    sdpa_mfma_kernel<<<grid, 256, 0, stream>>>(q, wsK, wsV, m, out);
}

// Round 3
// 410.453 us; speedup vs baseline: 1.2441x; 1.2441x over previous
//
#include <hip/hip_runtime.h>
#include <hip/hip_bf16.h>

#define BB 16
#define SS 2048
#define DD 64
#define NT_TILES (SS / 128)     // 16 k-tiles per batch
#define TILE_BYTES 16384        // one prepacked tile image (K or V^T), bf16 swizzled

typedef __attribute__((ext_vector_type(8)))  unsigned short ushort8;
typedef __attribute__((ext_vector_type(8)))  __bf16 bf16x8;
typedef __attribute__((ext_vector_type(16))) float f32x16;

static __device__ __forceinline__ unsigned short f2bf(float x) {
    return __builtin_bit_cast(unsigned short, __float2bfloat16(x));
}
static __device__ __forceinline__ unsigned pk2(float a, float b) {
    return (unsigned)f2bf(a) | ((unsigned)f2bf(b) << 16);
}
union F4 { float4 v; float a[4]; };

// ---------------------------------------------------------------------------
// KV pre-pack (unchanged, verified r1/r2): fp32 K,V -> bf16 swizzled 16KB
// tile images in workspace. One block per (k-tile, batch).
// ---------------------------------------------------------------------------
__global__ __launch_bounds__(256)
void prepack_kernel(const float* __restrict__ K, const float* __restrict__ V,
                    char* __restrict__ wsK, char* __restrict__ wsV) {
    __shared__ __align__(16) char smem[32768];
    char* Ks = smem;
    char* Vs = smem + 16384;
    const int t  = threadIdx.x;
    const int kt = blockIdx.x;
    const int b  = blockIdx.y;
    const float* Kg = K + (size_t)b * SS * DD;
    const float* Vg = V + (size_t)b * SS * DD;

    #pragma unroll
    for (int j = 0; j < 4; j++) {
        const int idx = 2 * t + 512 * j;
        const int row = idx >> 4;
        const int g   = (idx & 15) >> 1;
        const float* src = Kg + (size_t)(kt * 128) * DD + (size_t)idx * 4;
        F4 fa, fb; fa.v = *(const float4*)src; fb.v = *(const float4*)(src + 4);
        ushort8 u;
        #pragma unroll
        for (int e = 0; e < 4; e++) { u[e] = f2bf(fa.a[e]); u[e + 4] = f2bf(fb.a[e]); }
        *(ushort8*)(Ks + row * 128 + ((g ^ (row & 7)) * 16)) = u;
    }
    {
        const int d0v = (t & 15) * 4;
        const int kkb = (t >> 4) * 4;
        #pragma unroll
        for (int it2 = 0; it2 < 2; it2++) {
            const int kk = kkb + 64 * it2;
            const float* src = Vg + (size_t)(kt * 128 + kk) * DD + d0v;
            F4 r0, r1, r2, r3;
            r0.v = *(const float4*)(src);
            r1.v = *(const float4*)(src + DD);
            r2.v = *(const float4*)(src + 2 * DD);
            r3.v = *(const float4*)(src + 3 * DD);
            #pragma unroll
            for (int e = 0; e < 4; e++) {
                const int d = d0v + e;
                const uint2 wv = make_uint2(pk2(r0.a[e], r1.a[e]), pk2(r2.a[e], r3.a[e]));
                *(uint2*)(Vs + d * 256 + (((kk >> 3) ^ (d & 15)) * 16) + (kk & 7) * 2) = wv;
            }
        }
    }
    __syncthreads();
    char* dK = wsK + (size_t)(b * NT_TILES + kt) * TILE_BYTES;
    char* dV = wsV + (size_t)(b * NT_TILES + kt) * TILE_BYTES;
    #pragma unroll
    for (int j = 0; j < 4; j++) {
        *(float4*)(dK + t * 16 + j * 4096) = *(const float4*)(Ks + t * 16 + j * 4096);
        *(float4*)(dV + t * 16 + j * 4096) = *(const float4*)(Vs + t * 16 + j * 4096);
    }
}

// ---------------------------------------------------------------------------
// Mask pre-pack: 268 MB int32 bool -> 8 MB bitmask via wave64 __ballot.
// This is the ONLY kernel that touches the raw mask; it is a pure coalesced
// stream (fill-kernel regime, ~6.5 TB/s) with no latency-sensitive consumer.
// Output word Mb[b][ktkh][row] holds mask bits for columns 32*ktkh..+31 of
// `row` (ktkh = 4*kt + kh), bit i = column 32*ktkh + i.
// Block: 256 thr, 64 rows of one batch. Ballot -> per-lane word -> LDS
// transpose (pad 65 to kill bank conflicts) -> coalesced store.
// ---------------------------------------------------------------------------
__global__ __launch_bounds__(256)
void maskpack_kernel(const unsigned int* __restrict__ M, unsigned int* __restrict__ Mb) {
    __shared__ unsigned int T[64][65];
    const int t    = threadIdx.x;
    const int lane = t & 63;
    const int w    = t >> 6;
    const int b    = blockIdx.y;
    const int r0   = blockIdx.x * 64;

    #pragma unroll 1
    for (int i = 0; i < 16; ++i) {
        const int r = w + 4 * i;                    // 4 waves cover 64 rows
        const unsigned int* row = M + ((size_t)b * SS + r0 + r) * SS;
        unsigned myw = 0;
        #pragma unroll
        for (int c = 0; c < 32; ++c) {
            const unsigned v = __builtin_nontemporal_load(row + 64 * c + lane);
            const unsigned long long bits = __ballot(v != 0);
            // word ktkh = 2c   <- lo32 (cols 64c..+31), held by lane 2c
            // word ktkh = 2c+1 <- hi32 (cols 64c+32..+63), held by lane 2c+1
            const unsigned sel = (unsigned)(bits >> ((lane & 1) * 32));
            myw = ((lane >> 1) == c) ? sel : myw;
        }
        T[r][lane] = myw;                           // T[row][ktkh]
    }
    __syncthreads();
    #pragma unroll 1
    for (int i = 0; i < 16; ++i) {
        const int ktkh = w + 4 * i;
        Mb[((size_t)b * 64 + ktkh) * SS + r0 + lane] = T[lane][ktkh];
    }
}

// ---------------------------------------------------------------------------
// Main kernel: barrier-free k-loop, HAND-PIPELINED (r2 post-mortem: VGPR=52
// proved the compiler kept zero prefetch; 75% of 204us was latency stall).
// Ping-pong {ak[4], mw} tile sets at prefetch distance 1; V fragments issued
// at the top of each body so L2 latency hides under QK^T+exp. All loads are
// L2/L3-resident (K/V images 8MB, bitmask 8MB); mask = 1 VGPR/tile.
// ---------------------------------------------------------------------------
struct KTile { bf16x8 ak[4]; unsigned mw; };

__global__ __launch_bounds__(256, 4)
void sdpa_mfma_kernel(const float* __restrict__ Q, const char* __restrict__ wsK,
                      const char* __restrict__ wsV, const unsigned int* __restrict__ Mb,
                      float* __restrict__ O) {
    __shared__ __align__(16) char smem[25088];
    char* Qs = smem;                         // pre-loop only (4 KB, overlaps red)
    float* red  = (float*)smem;              // epilogue partials (24 KB)
    float* denx = (float*)(smem + 24576);    // epilogue den exchange (512 B)

    const int t    = threadIdx.x;
    const int lane = t & 63;
    const int l31  = lane & 31;
    const int half = lane >> 5;
    const int kh   = t >> 6;          // wave = k-chunk 32*kh of the 128-tile
    const int b    = blockIdx.y;
    const int q0   = blockIdx.x * 32;

    // ---- stage Q (pre-scaled by 1/temperature), swizzled bf16 ----
    {
        const int sr = t >> 3, sc = t & 7;
        const float* src = Q + ((size_t)b * SS + q0 + sr) * DD + sc * 8;
        F4 f0, f1; f0.v = *(const float4*)src; f1.v = *(const float4*)(src + 4);
        ushort8 u;
        #pragma unroll
        for (int e = 0; e < 4; e++) {
            u[e]     = f2bf(f0.a[e] * 0.125f);
            u[e + 4] = f2bf(f1.a[e] * 0.125f);
        }
        *(ushort8*)(Qs + sr * 128 + ((sc ^ (sr & 7)) * 16)) = u;
    }
    __syncthreads();

    const int qrow = l31;
    bf16x8 bq[4];
    #pragma unroll
    for (int dc = 0; dc < 4; dc++)
        bq[dc] = __builtin_bit_cast(bf16x8, *(const ushort8*)(
            Qs + qrow * 128 + (((2 * dc + half) ^ (qrow & 7)) * 16)));
    // (no barrier: smem untouched until the epilogue barrier)

    f32x16 On0, On1;
    #pragma unroll
    for (int i = 0; i < 16; i++) { On0[i] = 0.f; On1[i] = 0.f; }
    float den0 = 0.f, den1 = 0.f;

    const int krow = 32 * kh + l31;
    const char* tKbase = wsK + (size_t)b * NT_TILES * TILE_BYTES;
    const char* tVbase = wsV + (size_t)b * NT_TILES * TILE_BYTES;
    // bitmask word for (row=q0+l31, ktkh=4kt+kh); both halves broadcast-read it
    const unsigned int* Ml = Mb + ((size_t)b * 64 + kh) * SS + q0 + l31;

    auto load_kt = [&](KTile& T, int kt) {
        const char* tK = tKbase + (size_t)kt * TILE_BYTES;
        #pragma unroll
        for (int dc = 0; dc < 4; dc++)
            T.ak[dc] = __builtin_bit_cast(bf16x8, *(const ushort8*)(
                tK + krow * 128 + (((2 * dc + half) ^ (krow & 7)) * 16)));
        T.mw = Ml[(size_t)kt * 4 * SS];
    };

    auto tile_body = [&](const KTile& cur, KTile& nxt, const char* tV, int ktn) {
        // V frags first: L2 latency hides under QK^T + exp below
        bf16x8 av[2][2];
        #pragma unroll
        for (int s2 = 0; s2 < 2; s2++)
            #pragma unroll
            for (int dc = 0; dc < 2; dc++) {
                const int vrow = 32 * dc + l31;
                av[s2][dc] = __builtin_bit_cast(bf16x8, *(const ushort8*)(
                    tV + vrow * 256 + (((4 * kh + 2 * s2 + half) ^ (vrow & 15)) * 16)));
            }
        // prefetch next tile's K frags + mask word (distance 1)
        load_kt(nxt, ktn);

        // QK^T: S^T tile [32k x 32q]
        f32x16 S;
        #pragma unroll
        for (int i = 0; i < 16; i++) S[i] = 0.f;
        #pragma unroll
        for (int dc = 0; dc < 4; dc++)
            S = __builtin_amdgcn_mfma_f32_32x32x16_bf16(cur.ak[dc], bq[dc], S, 0, 0, 0);

        // mask + exp + denominator (C row = e + 8g + 4half -> bit 4half+8g+e)
        const unsigned mh = cur.mw >> (4 * half);
        float p[16];
        #pragma unroll
        for (int g = 0; g < 4; g++) {
            #pragma unroll
            for (int e = 0; e < 4; e++) {
                const float ev = __expf(S[4 * g + e]);
                const float pv = ((mh >> (8 * g + e)) & 1u) ? 1.0f : ev;
                p[4 * g + e] = pv;
                if (g & 1) den1 += pv; else den0 += pv;
            }
        }

        // P*V: B-operand frags via shfl_xor(32), 2 ksubs
        #pragma unroll
        for (int s2 = 0; s2 < 2; s2++) {
            const unsigned o0 = pk2(p[8 * s2 + 0], p[8 * s2 + 1]);
            const unsigned o1 = pk2(p[8 * s2 + 2], p[8 * s2 + 3]);
            const unsigned o2 = pk2(p[8 * s2 + 4], p[8 * s2 + 5]);
            const unsigned o3 = pk2(p[8 * s2 + 6], p[8 * s2 + 7]);
            const unsigned s0 = half ? o0 : o2;
            const unsigned s1 = half ? o1 : o3;
            const unsigned r0 = (unsigned)__shfl_xor((int)s0, 32, 64);
            const unsigned r1 = (unsigned)__shfl_xor((int)s1, 32, 64);
            uint4 bu;
            bu.x = half ? r0 : o0;
            bu.y = half ? r1 : o1;
            bu.z = half ? o2 : r0;
            bu.w = half ? o3 : r1;
            const bf16x8 bp = __builtin_bit_cast(bf16x8, bu);
            On0 = __builtin_amdgcn_mfma_f32_32x32x16_bf16(av[s2][0], bp, On0, 0, 0, 0);
            On1 = __builtin_amdgcn_mfma_f32_32x32x16_bf16(av[s2][1], bp, On1, 0, 0, 0);
        }
    };

    KTile TA, TB;
    load_kt(TA, 0);
    #pragma unroll 1
    for (int kt = 0; kt < NT_TILES; kt += 2) {
        tile_body(TA, TB, tVbase + (size_t)kt * TILE_BYTES, kt + 1);
        const int ktn = (kt + 2 < NT_TILES) ? (kt + 2) : (NT_TILES - 1); // clamp: dead load
        tile_body(TB, TA, tVbase + (size_t)(kt + 1) * TILE_BYTES, ktn);
    }

    // ---- epilogue: lane halves, then 4-way k-split reduction via LDS ----
    const float den_acc = den0 + den1;
    const float den_tot = den_acc + __shfl_xor(den_acc, 32, 64);

    __syncthreads();
    if (kh != 0) {
        #pragma unroll
        for (int dc = 0; dc < 2; dc++)
            #pragma unroll
            for (int g = 0; g < 4; g++) {
                const f32x16& Oc = dc ? On1 : On0;
                float4 st;
                st.x = Oc[4 * g + 0]; st.y = Oc[4 * g + 1];
                st.z = Oc[4 * g + 2]; st.w = Oc[4 * g + 3];
                *(float4*)((char*)red + (kh - 1) * 8192 + (dc * 4 + g) * 1024 + lane * 16) = st;
            }
        if (lane < 32) denx[kh * 32 + l31] = den_tot;
    }
    __syncthreads();
    if (kh == 0) {
        const float inv = 1.0f / (den_tot + denx[32 + l31] + denx[64 + l31] + denx[96 + l31]);
        float* Og = O + ((size_t)b * SS + q0 + qrow) * DD;
        #pragma unroll
        for (int dc = 0; dc < 2; dc++)
            #pragma unroll
            for (int g = 0; g < 4; g++) {
                const f32x16& Oc = dc ? On1 : On0;
                float4 st;
                st.x = Oc[4 * g + 0]; st.y = Oc[4 * g + 1];
                st.z = Oc[4 * g + 2]; st.w = Oc[4 * g + 3];
                #pragma unroll
                for (int w2 = 0; w2 < 3; w2++) {
                    const float4 pr = *(const float4*)((char*)red + w2 * 8192 +
                                                       (dc * 4 + g) * 1024 + lane * 16);
                    st.x += pr.x; st.y += pr.y; st.z += pr.z; st.w += pr.w;
                }
                st.x *= inv; st.y *= inv; st.z *= inv; st.w *= inv;
                // d = e + 8g + 4half + 32dc  (C-row formula)
                *(float4*)(Og + 32 * dc + 8 * g + 4 * half) = st;
            }
    }
}

extern "C" void kernel_launch(void* const* d_in, const int* in_sizes, int n_in,
                              void* d_out, int out_size, void* d_ws, size_t ws_size,
                              hipStream_t stream) {
    const float* q = (const float*)d_in[0];
    const float* k = (const float*)d_in[1];
    const float* v = (const float*)d_in[2];
    const unsigned int* m = (const unsigned int*)d_in[3];
    float* out = (float*)d_out;

    // workspace: 4 MB K images + 4 MB V images + 8 MB mask bitwords
    char* wsK = (char*)d_ws;
    char* wsV = wsK + (size_t)BB * NT_TILES * TILE_BYTES;
    unsigned int* wsM = (unsigned int*)(wsV + (size_t)BB * NT_TILES * TILE_BYTES);

    dim3 pgrid(NT_TILES, BB);           // 256 blocks
    prepack_kernel<<<pgrid, 256, 0, stream>>>(k, v, wsK, wsV);

    dim3 mgrid(SS / 64, BB);            // 512 blocks, pure mask stream
    maskpack_kernel<<<mgrid, 256, 0, stream>>>(m, wsM);

    dim3 grid(SS / 32, BB);             // 1024 blocks -> 4 per CU
    sdpa_mfma_kernel<<<grid, 256, 0, stream>>>(q, wsK, wsV, wsM, out);
}